// Round 15
// baseline (427.117 us; speedup 1.0000x reference)
//
#include <hip/hip_runtime.h>
#include <hip/hip_bf16.h>
#include <stdint.h>

typedef __attribute__((ext_vector_type(8))) __bf16 bf16x8;
typedef __attribute__((ext_vector_type(4))) __bf16 bf16x4;
typedef __attribute__((ext_vector_type(4))) float f32x4;

static constexpr int NN = 50000;
static constexpr int NE = 800000;
static constexpr int FX = 64;
static constexpr int FE = 32;
static constexpr int H  = 128;
static constexpr int NG = 128;
static constexpr int OD = 8;

// all six weight matrices -> transposed bf16 in one dispatch
__global__ void cvt_w_all(const float* __restrict__ a0, const float* __restrict__ a1,
                          const float* __restrict__ a2, const float* __restrict__ a3,
                          const float* __restrict__ a4, const float* __restrict__ a5,
                          __bf16* __restrict__ o0, __bf16* __restrict__ o1,
                          __bf16* __restrict__ o2, __bf16* __restrict__ o3,
                          __bf16* __restrict__ o4, __bf16* __restrict__ o5) {
  int i = blockIdx.x * blockDim.x + threadIdx.x;
  const float* src; __bf16* dst; int K; int base;
  if      (i <  12288) { src = a0; dst = o0; K =  96; base = 0; }
  else if (i <  32768) { src = a1; dst = o1; K = 160; base = 12288; }
  else if (i <  53248) { src = a2; dst = o2; K = 160; base = 32768; }
  else if (i <  69632) { src = a3; dst = o3; K = 128; base = 53248; }
  else if (i <  86016) { src = a4; dst = o4; K = 128; base = 69632; }
  else if (i < 102400) { src = a5; dst = o5; K = 128; base = 86016; }
  else return;
  int j = i - base;
  int n = j / K, k = j % K;
  dst[j] = (__bf16)src[k * 128 + n];
}

// ---------------- counting sort of edges by dst ----------------
__global__ void hist_build(const int* __restrict__ dst, int* __restrict__ hist) {
  int e = blockIdx.x * blockDim.x + threadIdx.x;
  if (e < NE) atomicAdd(&hist[dst[e]], 1);
}

__global__ void scan1(const int* __restrict__ hist, int* __restrict__ excl, int* __restrict__ btot) {
  __shared__ int tmp[256];
  int t = threadIdx.x;
  int i = blockIdx.x * 256 + t;
  int v = (i < NN) ? hist[i] : 0;
  tmp[t] = v;
  __syncthreads();
  for (int off = 1; off < 256; off <<= 1) {
    int add = (t >= off) ? tmp[t - off] : 0;
    __syncthreads();
    tmp[t] += add;
    __syncthreads();
  }
  if (i < NN) excl[i] = tmp[t] - v;
  if (t == 255) btot[blockIdx.x] = tmp[255];
}

__global__ void scan2(int* __restrict__ btot, int nb) {
  __shared__ int tmp[256];
  int t = threadIdx.x;
  int v = (t < nb) ? btot[t] : 0;
  tmp[t] = v;
  __syncthreads();
  for (int off = 1; off < 256; off <<= 1) {
    int add = (t >= off) ? tmp[t - off] : 0;
    __syncthreads();
    tmp[t] += add;
    __syncthreads();
  }
  if (t < nb) btot[t] = tmp[t] - v;
}

__global__ void scan3(const int* __restrict__ excl, const int* __restrict__ btot,
                      int* __restrict__ cursor) {
  int i = blockIdx.x * 256 + threadIdx.x;
  if (i < NN) cursor[i] = excl[i] + btot[blockIdx.x];
}

// scatter + fused edge_attr f32->bf16 gather into sorted order
__global__ void scatter_perm_ea(const int* __restrict__ src, const int* __restrict__ dst,
                                const float* __restrict__ ea,
                                int* __restrict__ cursor,
                                int* __restrict__ srcp, int* __restrict__ dstp,
                                __bf16* __restrict__ eabs) {
  int e = blockIdx.x * blockDim.x + threadIdx.x;
  if (e >= NE) return;
  int d = dst[e];
  int p = atomicAdd(&cursor[d], 1);
  srcp[p] = src[e];
  dstp[p] = d;
  const float* er = ea + (size_t)e * FE;
  __bf16* op = eabs + (size_t)p * FE;
#pragma unroll
  for (int c = 0; c < 4; ++c) {
    float4 v0 = *reinterpret_cast<const float4*>(er + c * 8);
    float4 v1 = *reinterpret_cast<const float4*>(er + c * 8 + 4);
    bf16x8 o;
    o[0] = (__bf16)v0.x; o[1] = (__bf16)v0.y; o[2] = (__bf16)v0.z; o[3] = (__bf16)v0.w;
    o[4] = (__bf16)v1.x; o[5] = (__bf16)v1.y; o[6] = (__bf16)v1.z; o[7] = (__bf16)v1.w;
    *reinterpret_cast<bf16x8*>(op + c * 8) = o;
  }
}

// ---------------- layer-0 node GEMM: Y = x @ W1h (reads f32 x directly) ----------------
template<int F, int DIN, bool F32IN>
__global__ __launch_bounds__(512) void node_gemm2(
    const void* __restrict__ Ain,
    const __bf16* __restrict__ wt,   // [128][DIN], h-part at col offset 0
    __bf16* __restrict__ Y)          // [NN][128]
{
  constexpr int APAD = F + 8;
  constexpr int KS   = F / 32;
  constexpr int CH   = F / 8;
  constexpr int AB   = 128 * APAD * 2;
  constexpr int OB   = 128 * 136 * 2;
  constexpr int SB   = (AB > OB) ? AB : OB;
  __shared__ __align__(16) char smem[SB];
  auto As  = reinterpret_cast<__bf16 (*)[APAD]>(smem);
  auto Ost = reinterpret_cast<__bf16 (*)[136]>(smem);

  const int tid   = threadIdx.x;
  const int lane  = tid & 63;
  const int w     = tid >> 6;
  const int m0    = blockIdx.x * 128;
  const int colq  = lane & 15;
  const int krow  = (lane >> 4) * 8;
  const int rbase = (lane >> 4) * 4;
  const int col   = w * 16 + colq;

  bf16x8 bf[KS];
#pragma unroll
  for (int ks = 0; ks < KS; ++ks)
    bf[ks] = *reinterpret_cast<const bf16x8*>(wt + (size_t)col * DIN + ks * 32 + krow);

  for (int i = tid; i < 128 * CH; i += 512) {
    int row = i / CH, c = i % CH;
    int g = m0 + row; if (g >= NN) g = NN - 1;
    if (F32IN) {
      const float* s = (const float*)Ain + (size_t)g * F + c * 8;
      float4 v0 = *reinterpret_cast<const float4*>(s);
      float4 v1 = *reinterpret_cast<const float4*>(s + 4);
      bf16x8 o;
      o[0] = (__bf16)v0.x; o[1] = (__bf16)v0.y; o[2] = (__bf16)v0.z; o[3] = (__bf16)v0.w;
      o[4] = (__bf16)v1.x; o[5] = (__bf16)v1.y; o[6] = (__bf16)v1.z; o[7] = (__bf16)v1.w;
      *reinterpret_cast<bf16x8*>(&As[row][c * 8]) = o;
    } else {
      *reinterpret_cast<bf16x8*>(&As[row][c * 8]) =
          *reinterpret_cast<const bf16x8*>((const __bf16*)Ain + (size_t)g * F + c * 8);
    }
  }
  __syncthreads();

  f32x4 acc[8];
#pragma unroll
  for (int mt = 0; mt < 8; ++mt) acc[mt] = (f32x4){0.f, 0.f, 0.f, 0.f};
#pragma unroll
  for (int ks = 0; ks < KS; ++ks)
#pragma unroll
    for (int mt = 0; mt < 8; ++mt) {
      bf16x8 a = *reinterpret_cast<const bf16x8*>(&As[mt * 16 + colq][ks * 32 + krow]);
      acc[mt] = __builtin_amdgcn_mfma_f32_16x16x32_bf16(a, bf[ks], acc[mt], 0, 0, 0);
    }
  __syncthreads();   // done reading As; Ost aliases it

#pragma unroll
  for (int mt = 0; mt < 8; ++mt)
#pragma unroll
    for (int r = 0; r < 4; ++r)
      Ost[mt * 16 + rbase + r][col] = (__bf16)acc[mt][r];
  __syncthreads();

  for (int i = tid; i < 128 * 16; i += 512) {
    int row = i >> 4, c = i & 15;
    int g = m0 + row;
    if (g < NN)
      *reinterpret_cast<bf16x8*>(Y + (size_t)g * H + c * 8) =
          *reinterpret_cast<const bf16x8*>(&Ost[row][c * 8]);
  }
}

// ---------------- node kernel: h = relu(aggH@W2 + deg*b2); Y = h@W1h ----------------
// Also zeroes aggH rows after staging (replaces the inter-layer memset).
__global__ __launch_bounds__(512) void node_wy_t(
    float* __restrict__ aggH,          // [NN][128] f32 (read then zeroed)
    const int* __restrict__ deg,
    const __bf16* __restrict__ w2t,    // [128][128]
    const float* __restrict__ b2,
    const __bf16* __restrict__ w1t,    // [128][160], h-part at 0
    __bf16* __restrict__ Y)
{
  __shared__ __bf16 Ast[128][136];
  __shared__ __bf16 Hst[128][136];
  __shared__ int deg_s[128];

  const int tid   = threadIdx.x;
  const int lane  = tid & 63;
  const int w     = tid >> 6;
  const int m0    = blockIdx.x * 128;
  const int colq  = lane & 15;
  const int krow  = (lane >> 4) * 8;
  const int rbase = (lane >> 4) * 4;
  const int col   = w * 16 + colq;

  // stage aggH (f32 -> bf16) and zero the rows we own
  for (int i = tid; i < 128 * 16; i += 512) {
    int row = i >> 4, cb = (i & 15) * 8;
    int g = m0 + row;
    bool valid = g < NN;
    int gc = valid ? g : NN - 1;
    float* s = aggH + (size_t)gc * H + cb;
    float4 v0 = *reinterpret_cast<const float4*>(s);
    float4 v1 = *reinterpret_cast<const float4*>(s + 4);
    bf16x8 o;
    o[0] = (__bf16)v0.x; o[1] = (__bf16)v0.y; o[2] = (__bf16)v0.z; o[3] = (__bf16)v0.w;
    o[4] = (__bf16)v1.x; o[5] = (__bf16)v1.y; o[6] = (__bf16)v1.z; o[7] = (__bf16)v1.w;
    *reinterpret_cast<bf16x8*>(&Ast[row][cb]) = o;
    if (valid) {
      *reinterpret_cast<float4*>(s)     = (float4){0.f, 0.f, 0.f, 0.f};
      *reinterpret_cast<float4*>(s + 4) = (float4){0.f, 0.f, 0.f, 0.f};
    }
  }
  if (tid < 128) {
    int g = m0 + tid;
    deg_s[tid] = (g < NN) ? deg[g] : 0;
  }
  __syncthreads();

  bf16x8 w2f[4];
#pragma unroll
  for (int ks = 0; ks < 4; ++ks)
    w2f[ks] = *reinterpret_cast<const bf16x8*>(w2t + (size_t)col * H + ks * 32 + krow);
  const float b2s = b2[col];

  f32x4 acc[8];
#pragma unroll
  for (int mt = 0; mt < 8; ++mt) acc[mt] = (f32x4){0.f, 0.f, 0.f, 0.f};
#pragma unroll
  for (int ks = 0; ks < 4; ++ks)
#pragma unroll
    for (int mt = 0; mt < 8; ++mt) {
      bf16x8 a = *reinterpret_cast<const bf16x8*>(&Ast[mt * 16 + colq][ks * 32 + krow]);
      acc[mt] = __builtin_amdgcn_mfma_f32_16x16x32_bf16(a, w2f[ks], acc[mt], 0, 0, 0);
    }

#pragma unroll
  for (int mt = 0; mt < 8; ++mt)
#pragma unroll
    for (int r = 0; r < 4; ++r) {
      int row = mt * 16 + rbase + r;
      float v = acc[mt][r] + (float)deg_s[row] * b2s;
      Hst[row][col] = (__bf16)fmaxf(v, 0.f);
    }
  __syncthreads();   // Hst complete; Ast dead

  bf16x8 w1f[4];
#pragma unroll
  for (int ks = 0; ks < 4; ++ks)
    w1f[ks] = *reinterpret_cast<const bf16x8*>(w1t + (size_t)col * 160 + ks * 32 + krow);

  f32x4 acc2[8];
#pragma unroll
  for (int mt = 0; mt < 8; ++mt) acc2[mt] = (f32x4){0.f, 0.f, 0.f, 0.f};
#pragma unroll
  for (int ks = 0; ks < 4; ++ks)
#pragma unroll
    for (int mt = 0; mt < 8; ++mt) {
      bf16x8 a = *reinterpret_cast<const bf16x8*>(&Hst[mt * 16 + colq][ks * 32 + krow]);
      acc2[mt] = __builtin_amdgcn_mfma_f32_16x16x32_bf16(a, w1f[ks], acc2[mt], 0, 0, 0);
    }

  // Ost overlays Ast
#pragma unroll
  for (int mt = 0; mt < 8; ++mt)
#pragma unroll
    for (int r = 0; r < 4; ++r)
      Ast[mt * 16 + rbase + r][col] = (__bf16)acc2[mt][r];
  __syncthreads();

  for (int i = tid; i < 128 * 16; i += 512) {
    int row = i >> 4, cb = (i & 15) * 8;
    int g = m0 + row;
    if (g < NN)
      *reinterpret_cast<bf16x8*>(Y + (size_t)g * H + cb) =
          *reinterpret_cast<const bf16x8*>(&Ast[row][cb]);
  }
}

// ---------------- final node stage fused with pooling ----------------
__global__ __launch_bounds__(512) void node_pool(
    const float* __restrict__ aggH,
    const int* __restrict__ deg,
    const __bf16* __restrict__ w2t,
    const float* __restrict__ b2,
    const int* __restrict__ batch,
    float* __restrict__ sums)          // [NG][128]
{
  __shared__ __bf16 Ast[128][136];
  __shared__ int deg_s[128];
  __shared__ int bs[128];

  const int tid   = threadIdx.x;
  const int lane  = tid & 63;
  const int w     = tid >> 6;
  const int m0    = blockIdx.x * 128;
  const int colq  = lane & 15;
  const int krow  = (lane >> 4) * 8;
  const int rbase = (lane >> 4) * 4;
  const int col   = w * 16 + colq;

  for (int i = tid; i < 128 * 16; i += 512) {
    int row = i >> 4, cb = (i & 15) * 8;
    int g = m0 + row; if (g >= NN) g = NN - 1;
    const float* s = aggH + (size_t)g * H + cb;
    float4 v0 = *reinterpret_cast<const float4*>(s);
    float4 v1 = *reinterpret_cast<const float4*>(s + 4);
    bf16x8 o;
    o[0] = (__bf16)v0.x; o[1] = (__bf16)v0.y; o[2] = (__bf16)v0.z; o[3] = (__bf16)v0.w;
    o[4] = (__bf16)v1.x; o[5] = (__bf16)v1.y; o[6] = (__bf16)v1.z; o[7] = (__bf16)v1.w;
    *reinterpret_cast<bf16x8*>(&Ast[row][cb]) = o;
  }
  if (tid < 128) {
    int g = m0 + tid;
    deg_s[tid] = (g < NN) ? deg[g] : 0;
    bs[tid]    = (g < NN) ? batch[g] : -1;
  }
  __syncthreads();

  bf16x8 w2f[4];
#pragma unroll
  for (int ks = 0; ks < 4; ++ks)
    w2f[ks] = *reinterpret_cast<const bf16x8*>(w2t + (size_t)col * H + ks * 32 + krow);
  const float b2s = b2[col];

  f32x4 acc[8];
#pragma unroll
  for (int mt = 0; mt < 8; ++mt) acc[mt] = (f32x4){0.f, 0.f, 0.f, 0.f};
#pragma unroll
  for (int ks = 0; ks < 4; ++ks)
#pragma unroll
    for (int mt = 0; mt < 8; ++mt) {
      bf16x8 a = *reinterpret_cast<const bf16x8*>(&Ast[mt * 16 + colq][ks * 32 + krow]);
      acc[mt] = __builtin_amdgcn_mfma_f32_16x16x32_bf16(a, w2f[ks], acc[mt], 0, 0, 0);
    }

  // run-accumulate relu(v) by graph id over this thread's 32 ascending rows
  float run = 0.f;
  int cur = -2;
#pragma unroll
  for (int mt = 0; mt < 8; ++mt)
#pragma unroll
    for (int r = 0; r < 4; ++r) {
      int row = mt * 16 + rbase + r;
      int b = bs[row];
      float v = fmaxf(acc[mt][r] + (float)deg_s[row] * b2s, 0.f);
      if (b != cur) {
        if (cur >= 0) atomicAdd(&sums[cur * H + col], run);
        run = 0.f;
        cur = b;
      }
      if (b >= 0) run += v;
    }
  if (cur >= 0) atomicAdd(&sums[cur * H + col], run);
}

// ---------------- edge kernel (edge_mlp4; TPB=6 -> ~one dispatch wave) ----------------
template<int DIN>
__global__ __launch_bounds__(512) void edge_mlp4(
    const __bf16* __restrict__ Yb,    // [NN][128]
    const __bf16* __restrict__ eabs,  // [NE][32] sorted
    const int* __restrict__ srcp, const int* __restrict__ dstp,
    const __bf16* __restrict__ w1t,   // [128][DIN]; e-part at col offset F
    const float* __restrict__ b1,
    float* __restrict__ aggH,         // [NN][128] f32
    int ntiles)
{
  constexpr int F = DIN - 32;
  constexpr int TPB = 6;
  __shared__ __bf16 Ylds[128][128];
  __shared__ int dst_s[128];

  const int tid   = threadIdx.x;
  const int lane  = tid & 63;
  const int w     = tid >> 6;
  const int colq  = lane & 15;
  const int krow  = (lane >> 4) * 8;
  const int rbase = (lane >> 4) * 4;
  const int col   = w * 16 + colq;

  const bf16x8 b1f = *reinterpret_cast<const bf16x8*>(w1t + (size_t)col * DIN + F + krow);
  const float  b1s = b1[col];

  const int yrow = tid >> 4;    // 0..31
  const int yc   = tid & 15;
  const int drow = tid & 127;

  int t0 = blockIdx.x * TPB;
  int t1 = t0 + TPB; if (t1 > ntiles) t1 = ntiles;
  if (t0 >= ntiles) return;

  // ---- prologue: tile t0 data; t0+1 src indices ----
  int e0 = t0 * 128;
  int sA[4];
#pragma unroll
  for (int k = 0; k < 4; ++k) sA[k] = srcp[e0 + yrow + 32 * k];
  int dreg = dstp[e0 + drow];
  bf16x8 yreg[4];
#pragma unroll
  for (int k = 0; k < 4; ++k)
    yreg[k] = *reinterpret_cast<const bf16x8*>(Yb + (size_t)sA[k] * H + yc * 8);
  bf16x8 aef[8];
#pragma unroll
  for (int mt = 0; mt < 8; ++mt)
    aef[mt] = *reinterpret_cast<const bf16x8*>(eabs + (size_t)(e0 + mt * 16 + colq) * FE + krow);
  {
    int e0n = (t0 + 1 < t1) ? (t0 + 1) * 128 : e0;
#pragma unroll
    for (int k = 0; k < 4; ++k) sA[k] = srcp[e0n + yrow + 32 * k];
  }

  for (int t = t0; t < t1; ++t) {
    __syncthreads();                     // Ylds free (prev reduce done)
    // stage Y regs -> LDS (rot-swizzled chunks)
#pragma unroll
    for (int k = 0; k < 4; ++k) {
      int row = yrow + 32 * k;
      int cb = (yc * 8 + ((row >> 2) & 3) * 16) & 127;
      *reinterpret_cast<bf16x8*>(&Ylds[row][cb]) = yreg[k];
    }
    if (tid < 128) dst_s[tid] = dreg;
    __syncthreads();                     // stage visible

    // issue next-tile Y/dst gathers (hide under compute)
    if (t + 1 < t1) {
      int e1 = (t + 1) * 128;
#pragma unroll
      for (int k = 0; k < 4; ++k)
        yreg[k] = *reinterpret_cast<const bf16x8*>(Yb + (size_t)sA[k] * H + yc * 8);
      dreg = dstp[e1 + drow];
      int e2 = (t + 2 < t1) ? (t + 2) * 128 : e1;
#pragma unroll
      for (int k = 0; k < 4; ++k) sA[k] = srcp[e2 + yrow + 32 * k];
    }

    // GEMM1e: ea @ W1e + b1 (K=32, one step)
    f32x4 acc[8];
#pragma unroll
    for (int mt = 0; mt < 8; ++mt) acc[mt] = (f32x4){b1s, b1s, b1s, b1s};
#pragma unroll
    for (int mt = 0; mt < 8; ++mt)
      acc[mt] = __builtin_amdgcn_mfma_f32_16x16x32_bf16(aef[mt], b1f, acc[mt], 0, 0, 0);

    // prefetch next-tile ea fragments (aef now dead)
    if (t + 1 < t1) {
      int e1 = (t + 1) * 128;
#pragma unroll
      for (int mt = 0; mt < 8; ++mt)
        aef[mt] = *reinterpret_cast<const bf16x8*>(eabs + (size_t)(e1 + mt * 16 + colq) * FE + krow);
    }

    // in-place: Ylds = relu(Y + ea@W1e + b1)
#pragma unroll
    for (int mt = 0; mt < 8; ++mt)
#pragma unroll
      for (int r = 0; r < 4; ++r) {
        int row = mt * 16 + rbase + r;
        int cs = (col + ((row >> 2) & 3) * 16) & 127;
        float v = (float)Ylds[row][cs] + acc[mt][r];
        Ylds[row][cs] = (__bf16)fmaxf(v, 0.f);
      }
    __syncthreads();                     // Mid complete

    // segment reduce over sorted dst: 4 threads/col, 32 rows each
    {
      const int rc = tid & 127;
      const int r0 = (tid >> 7) * 32;
      float s = 0.f;
      int d = dst_s[r0];
#pragma unroll 4
      for (int r = r0; r < r0 + 32; ++r) {
        int dn = dst_s[r];
        float v = (float)Ylds[r][(rc + ((r >> 2) & 3) * 16) & 127];
        if (dn != d) { atomicAdd(aggH + (size_t)d * H + rc, s); s = 0.f; d = dn; }
        s += v;
      }
      atomicAdd(aggH + (size_t)d * H + rc, s);
    }
  }
}

// ---------------- head: counts via binary search over sorted batch ----------------
__global__ void final_kernel(const float* __restrict__ sums, const int* __restrict__ batch,
                             const float* __restrict__ lw, const float* __restrict__ lb,
                             float* __restrict__ out) {
  int idx = blockIdx.x * blockDim.x + threadIdx.x;
  if (idx >= NG * OD) return;
  int g = idx / OD, o = idx % OD;
  auto lbs = [&](int key) {
    int lo = 0, hi = NN;
    while (lo < hi) {
      int mid = (lo + hi) >> 1;
      if (batch[mid] < key) lo = mid + 1; else hi = mid;
    }
    return lo;
  };
  int c = lbs(g + 1) - lbs(g);
  float inv = 1.f / fmaxf((float)c, 1.f);
  float s = 0.f;
#pragma unroll 8
  for (int k = 0; k < H; ++k)
    s += sums[g * H + k] * lw[k * OD + o];
  out[idx] = s * inv + lb[o];
}

// ---------------- launcher ----------------
extern "C" void kernel_launch(void* const* d_in, const int* in_sizes, int n_in,
                              void* d_out, int out_size, void* d_ws, size_t ws_size,
                              hipStream_t stream) {
  const float* x   = (const float*)d_in[0];
  const int*   ei  = (const int*)d_in[1];
  const float* ea  = (const float*)d_in[2];
  const int*   bat = (const int*)d_in[3];
  const float* w1[3] = {(const float*)d_in[4], (const float*)d_in[8],  (const float*)d_in[12]};
  const float* b1[3] = {(const float*)d_in[5], (const float*)d_in[9],  (const float*)d_in[13]};
  const float* w2[3] = {(const float*)d_in[6], (const float*)d_in[10], (const float*)d_in[14]};
  const float* b2[3] = {(const float*)d_in[7], (const float*)d_in[11], (const float*)d_in[15]};
  const float* lw  = (const float*)d_in[16];
  const float* lb  = (const float*)d_in[17];
  float* out = (float*)d_out;

  char* ws = (char*)d_ws;
  size_t off = 0;
  auto alloc = [&](size_t bytes) -> void* {
    void* p = ws + off;
    off = (off + bytes + 255) & ~(size_t)255;
    return p;
  };
  __bf16* Yb   = (__bf16*)alloc((size_t)NN * H * 2);
  __bf16* eabs = (__bf16*)alloc((size_t)NE * FE * 2);
  __bf16* w1t[3]; __bf16* w2t[3];
  for (int l = 0; l < 3; ++l) {
    w1t[l] = (__bf16*)alloc(128 * 160 * 2);
    w2t[l] = (__bf16*)alloc(128 * 128 * 2);
  }
  // contiguous zero-init region: agg | sums | hist (single memset covers all)
  size_t zoff0 = off;
  float* agg  = (float*)alloc((size_t)NN * H * 4);
  float* sums = (float*)alloc(NG * H * 4);
  int*   hist = (int*)  alloc((size_t)NN * 4);
  size_t zbytes = off - zoff0;
  int* excl   = (int*)alloc((size_t)NN * 4);
  int* btot   = (int*)alloc(256 * 4);
  int* cursor = (int*)alloc((size_t)NN * 4);
  int* srcp   = (int*)alloc((size_t)NE * 4);
  int* dstp   = (int*)alloc((size_t)NE * 4);

  const int* src = ei;
  const int* dst = ei + NE;
  const int NB_SCAN = (NN + 255) / 256;
  const int NTILES = NE / 128;             // 6250
  const int EGRID  = (NTILES + 5) / 6;     // 1042 (TPB=6, ~one dispatch wave)
  const int NGRID  = (NN + 127) / 128;     // 391

  // one memset zeroes agg + sums + hist
  hipMemsetAsync(agg, 0, zbytes, stream);

  // weight conversions (single dispatch)
  cvt_w_all<<<(102400 + 255) / 256, 256, 0, stream>>>(
      w1[0], w1[1], w1[2], w2[0], w2[1], w2[2],
      w1t[0], w1t[1], w1t[2], w2t[0], w2t[1], w2t[2]);

  // counting sort by dst (hist doubles as deg) + fused ea convert/gather
  hist_build<<<(NE + 255) / 256, 256, 0, stream>>>(dst, hist);
  scan1<<<NB_SCAN, 256, 0, stream>>>(hist, excl, btot);
  scan2<<<1, 256, 0, stream>>>(btot, NB_SCAN);
  scan3<<<NB_SCAN, 256, 0, stream>>>(excl, btot, cursor);
  scatter_perm_ea<<<(NE + 255) / 256, 256, 0, stream>>>(src, dst, ea, cursor, srcp, dstp, eabs);

  // ---- layer 0 (f32 x staged+converted in-kernel) ----
  node_gemm2<64, 96, true><<<NGRID, 512, 0, stream>>>(x, w1t[0], Yb);
  edge_mlp4<96><<<EGRID, 512, 0, stream>>>(Yb, eabs, srcp, dstp, w1t[0], b1[0], agg, NTILES);

  // ---- layers 1,2 (node_wy_t zeroes agg for the next accumulate) ----
  for (int l = 1; l < 3; ++l) {
    node_wy_t<<<NGRID, 512, 0, stream>>>(agg, hist, w2t[l - 1], b2[l - 1], w1t[l], Yb);
    edge_mlp4<160><<<EGRID, 512, 0, stream>>>(Yb, eabs, srcp, dstp, w1t[l], b1[l], agg, NTILES);
  }

  // ---- final W2 stage fused with pooling + head ----
  node_pool<<<NGRID, 512, 0, stream>>>(agg, hist, w2t[2], b2[2], bat, sums);
  final_kernel<<<(NG * OD + 255) / 256, 256, 0, stream>>>(sums, bat, lw, lb, out);
}

// Round 16
// 410.136 us; speedup vs baseline: 1.0414x; 1.0414x over previous
//
#include <hip/hip_runtime.h>
#include <hip/hip_bf16.h>
#include <stdint.h>

typedef __attribute__((ext_vector_type(8))) __bf16 bf16x8;
typedef __attribute__((ext_vector_type(4))) __bf16 bf16x4;
typedef __attribute__((ext_vector_type(4))) float f32x4;

static constexpr int NN = 50000;
static constexpr int NE = 800000;
static constexpr int FX = 64;
static constexpr int FE = 32;
static constexpr int H  = 128;
static constexpr int NG = 128;
static constexpr int OD = 8;

// all six weight matrices -> transposed bf16 in one dispatch
__global__ void cvt_w_all(const float* __restrict__ a0, const float* __restrict__ a1,
                          const float* __restrict__ a2, const float* __restrict__ a3,
                          const float* __restrict__ a4, const float* __restrict__ a5,
                          __bf16* __restrict__ o0, __bf16* __restrict__ o1,
                          __bf16* __restrict__ o2, __bf16* __restrict__ o3,
                          __bf16* __restrict__ o4, __bf16* __restrict__ o5) {
  int i = blockIdx.x * blockDim.x + threadIdx.x;
  const float* src; __bf16* dst; int K; int base;
  if      (i <  12288) { src = a0; dst = o0; K =  96; base = 0; }
  else if (i <  32768) { src = a1; dst = o1; K = 160; base = 12288; }
  else if (i <  53248) { src = a2; dst = o2; K = 160; base = 32768; }
  else if (i <  69632) { src = a3; dst = o3; K = 128; base = 53248; }
  else if (i <  86016) { src = a4; dst = o4; K = 128; base = 69632; }
  else if (i < 102400) { src = a5; dst = o5; K = 128; base = 86016; }
  else return;
  int j = i - base;
  int n = j / K, k = j % K;
  dst[j] = (__bf16)src[k * 128 + n];
}

// ---------------- counting sort of edges by dst ----------------
__global__ void hist_build(const int* __restrict__ dst, int* __restrict__ hist) {
  int e = blockIdx.x * blockDim.x + threadIdx.x;
  if (e < NE) atomicAdd(&hist[dst[e]], 1);
}

__global__ void scan1(const int* __restrict__ hist, int* __restrict__ excl, int* __restrict__ btot) {
  __shared__ int tmp[256];
  int t = threadIdx.x;
  int i = blockIdx.x * 256 + t;
  int v = (i < NN) ? hist[i] : 0;
  tmp[t] = v;
  __syncthreads();
  for (int off = 1; off < 256; off <<= 1) {
    int add = (t >= off) ? tmp[t - off] : 0;
    __syncthreads();
    tmp[t] += add;
    __syncthreads();
  }
  if (i < NN) excl[i] = tmp[t] - v;
  if (t == 255) btot[blockIdx.x] = tmp[255];
}

__global__ void scan2(int* __restrict__ btot, int nb) {
  __shared__ int tmp[256];
  int t = threadIdx.x;
  int v = (t < nb) ? btot[t] : 0;
  tmp[t] = v;
  __syncthreads();
  for (int off = 1; off < 256; off <<= 1) {
    int add = (t >= off) ? tmp[t - off] : 0;
    __syncthreads();
    tmp[t] += add;
    __syncthreads();
  }
  if (t < nb) btot[t] = tmp[t] - v;
}

__global__ void scan3(const int* __restrict__ excl, const int* __restrict__ btot,
                      int* __restrict__ cursor) {
  int i = blockIdx.x * 256 + threadIdx.x;
  if (i < NN) cursor[i] = excl[i] + btot[blockIdx.x];
}

// scatter + fused edge_attr f32->bf16 gather into sorted order
__global__ void scatter_perm_ea(const int* __restrict__ src, const int* __restrict__ dst,
                                const float* __restrict__ ea,
                                int* __restrict__ cursor,
                                int* __restrict__ srcp, int* __restrict__ dstp,
                                __bf16* __restrict__ eabs) {
  int e = blockIdx.x * blockDim.x + threadIdx.x;
  if (e >= NE) return;
  int d = dst[e];
  int p = atomicAdd(&cursor[d], 1);
  srcp[p] = src[e];
  dstp[p] = d;
  const float* er = ea + (size_t)e * FE;
  __bf16* op = eabs + (size_t)p * FE;
#pragma unroll
  for (int c = 0; c < 4; ++c) {
    float4 v0 = *reinterpret_cast<const float4*>(er + c * 8);
    float4 v1 = *reinterpret_cast<const float4*>(er + c * 8 + 4);
    bf16x8 o;
    o[0] = (__bf16)v0.x; o[1] = (__bf16)v0.y; o[2] = (__bf16)v0.z; o[3] = (__bf16)v0.w;
    o[4] = (__bf16)v1.x; o[5] = (__bf16)v1.y; o[6] = (__bf16)v1.z; o[7] = (__bf16)v1.w;
    *reinterpret_cast<bf16x8*>(op + c * 8) = o;
  }
}

// ---------------- layer-0 node GEMM: Y = x @ W1h (reads f32 x directly) ----------------
template<int F, int DIN, bool F32IN>
__global__ __launch_bounds__(512) void node_gemm2(
    const void* __restrict__ Ain,
    const __bf16* __restrict__ wt,   // [128][DIN], h-part at col offset 0
    __bf16* __restrict__ Y)          // [NN][128]
{
  constexpr int APAD = F + 8;
  constexpr int KS   = F / 32;
  constexpr int CH   = F / 8;
  constexpr int AB   = 128 * APAD * 2;
  constexpr int OB   = 128 * 136 * 2;
  constexpr int SB   = (AB > OB) ? AB : OB;
  __shared__ __align__(16) char smem[SB];
  auto As  = reinterpret_cast<__bf16 (*)[APAD]>(smem);
  auto Ost = reinterpret_cast<__bf16 (*)[136]>(smem);

  const int tid   = threadIdx.x;
  const int lane  = tid & 63;
  const int w     = tid >> 6;
  const int m0    = blockIdx.x * 128;
  const int colq  = lane & 15;
  const int krow  = (lane >> 4) * 8;
  const int rbase = (lane >> 4) * 4;
  const int col   = w * 16 + colq;

  bf16x8 bf[KS];
#pragma unroll
  for (int ks = 0; ks < KS; ++ks)
    bf[ks] = *reinterpret_cast<const bf16x8*>(wt + (size_t)col * DIN + ks * 32 + krow);

  for (int i = tid; i < 128 * CH; i += 512) {
    int row = i / CH, c = i % CH;
    int g = m0 + row; if (g >= NN) g = NN - 1;
    if (F32IN) {
      const float* s = (const float*)Ain + (size_t)g * F + c * 8;
      float4 v0 = *reinterpret_cast<const float4*>(s);
      float4 v1 = *reinterpret_cast<const float4*>(s + 4);
      bf16x8 o;
      o[0] = (__bf16)v0.x; o[1] = (__bf16)v0.y; o[2] = (__bf16)v0.z; o[3] = (__bf16)v0.w;
      o[4] = (__bf16)v1.x; o[5] = (__bf16)v1.y; o[6] = (__bf16)v1.z; o[7] = (__bf16)v1.w;
      *reinterpret_cast<bf16x8*>(&As[row][c * 8]) = o;
    } else {
      *reinterpret_cast<bf16x8*>(&As[row][c * 8]) =
          *reinterpret_cast<const bf16x8*>((const __bf16*)Ain + (size_t)g * F + c * 8);
    }
  }
  __syncthreads();

  f32x4 acc[8];
#pragma unroll
  for (int mt = 0; mt < 8; ++mt) acc[mt] = (f32x4){0.f, 0.f, 0.f, 0.f};
#pragma unroll
  for (int ks = 0; ks < KS; ++ks)
#pragma unroll
    for (int mt = 0; mt < 8; ++mt) {
      bf16x8 a = *reinterpret_cast<const bf16x8*>(&As[mt * 16 + colq][ks * 32 + krow]);
      acc[mt] = __builtin_amdgcn_mfma_f32_16x16x32_bf16(a, bf[ks], acc[mt], 0, 0, 0);
    }
  __syncthreads();   // done reading As; Ost aliases it

#pragma unroll
  for (int mt = 0; mt < 8; ++mt)
#pragma unroll
    for (int r = 0; r < 4; ++r)
      Ost[mt * 16 + rbase + r][col] = (__bf16)acc[mt][r];
  __syncthreads();

  for (int i = tid; i < 128 * 16; i += 512) {
    int row = i >> 4, c = i & 15;
    int g = m0 + row;
    if (g < NN)
      *reinterpret_cast<bf16x8*>(Y + (size_t)g * H + c * 8) =
          *reinterpret_cast<const bf16x8*>(&Ost[row][c * 8]);
  }
}

// ---------------- node kernel: h = relu(aggH@W2 + deg*b2); Y = h@W1h ----------------
// Also zeroes aggH rows after staging (replaces the inter-layer memset).
__global__ __launch_bounds__(512) void node_wy_t(
    float* __restrict__ aggH,          // [NN][128] f32 (read then zeroed)
    const int* __restrict__ deg,
    const __bf16* __restrict__ w2t,    // [128][128]
    const float* __restrict__ b2,
    const __bf16* __restrict__ w1t,    // [128][160], h-part at 0
    __bf16* __restrict__ Y)
{
  __shared__ __bf16 Ast[128][136];
  __shared__ __bf16 Hst[128][136];
  __shared__ int deg_s[128];

  const int tid   = threadIdx.x;
  const int lane  = tid & 63;
  const int w     = tid >> 6;
  const int m0    = blockIdx.x * 128;
  const int colq  = lane & 15;
  const int krow  = (lane >> 4) * 8;
  const int rbase = (lane >> 4) * 4;
  const int col   = w * 16 + colq;

  // stage aggH (f32 -> bf16) and zero the rows we own
  for (int i = tid; i < 128 * 16; i += 512) {
    int row = i >> 4, cb = (i & 15) * 8;
    int g = m0 + row;
    bool valid = g < NN;
    int gc = valid ? g : NN - 1;
    float* s = aggH + (size_t)gc * H + cb;
    float4 v0 = *reinterpret_cast<const float4*>(s);
    float4 v1 = *reinterpret_cast<const float4*>(s + 4);
    bf16x8 o;
    o[0] = (__bf16)v0.x; o[1] = (__bf16)v0.y; o[2] = (__bf16)v0.z; o[3] = (__bf16)v0.w;
    o[4] = (__bf16)v1.x; o[5] = (__bf16)v1.y; o[6] = (__bf16)v1.z; o[7] = (__bf16)v1.w;
    *reinterpret_cast<bf16x8*>(&Ast[row][cb]) = o;
    if (valid) {
      *reinterpret_cast<float4*>(s)     = (float4){0.f, 0.f, 0.f, 0.f};
      *reinterpret_cast<float4*>(s + 4) = (float4){0.f, 0.f, 0.f, 0.f};
    }
  }
  if (tid < 128) {
    int g = m0 + tid;
    deg_s[tid] = (g < NN) ? deg[g] : 0;
  }
  __syncthreads();

  bf16x8 w2f[4];
#pragma unroll
  for (int ks = 0; ks < 4; ++ks)
    w2f[ks] = *reinterpret_cast<const bf16x8*>(w2t + (size_t)col * H + ks * 32 + krow);
  const float b2s = b2[col];

  f32x4 acc[8];
#pragma unroll
  for (int mt = 0; mt < 8; ++mt) acc[mt] = (f32x4){0.f, 0.f, 0.f, 0.f};
#pragma unroll
  for (int ks = 0; ks < 4; ++ks)
#pragma unroll
    for (int mt = 0; mt < 8; ++mt) {
      bf16x8 a = *reinterpret_cast<const bf16x8*>(&Ast[mt * 16 + colq][ks * 32 + krow]);
      acc[mt] = __builtin_amdgcn_mfma_f32_16x16x32_bf16(a, w2f[ks], acc[mt], 0, 0, 0);
    }

#pragma unroll
  for (int mt = 0; mt < 8; ++mt)
#pragma unroll
    for (int r = 0; r < 4; ++r) {
      int row = mt * 16 + rbase + r;
      float v = acc[mt][r] + (float)deg_s[row] * b2s;
      Hst[row][col] = (__bf16)fmaxf(v, 0.f);
    }
  __syncthreads();   // Hst complete; Ast dead

  bf16x8 w1f[4];
#pragma unroll
  for (int ks = 0; ks < 4; ++ks)
    w1f[ks] = *reinterpret_cast<const bf16x8*>(w1t + (size_t)col * 160 + ks * 32 + krow);

  f32x4 acc2[8];
#pragma unroll
  for (int mt = 0; mt < 8; ++mt) acc2[mt] = (f32x4){0.f, 0.f, 0.f, 0.f};
#pragma unroll
  for (int ks = 0; ks < 4; ++ks)
#pragma unroll
    for (int mt = 0; mt < 8; ++mt) {
      bf16x8 a = *reinterpret_cast<const bf16x8*>(&Hst[mt * 16 + colq][ks * 32 + krow]);
      acc2[mt] = __builtin_amdgcn_mfma_f32_16x16x32_bf16(a, w1f[ks], acc2[mt], 0, 0, 0);
    }

  // Ost overlays Ast
#pragma unroll
  for (int mt = 0; mt < 8; ++mt)
#pragma unroll
    for (int r = 0; r < 4; ++r)
      Ast[mt * 16 + rbase + r][col] = (__bf16)acc2[mt][r];
  __syncthreads();

  for (int i = tid; i < 128 * 16; i += 512) {
    int row = i >> 4, cb = (i & 15) * 8;
    int g = m0 + row;
    if (g < NN)
      *reinterpret_cast<bf16x8*>(Y + (size_t)g * H + cb) =
          *reinterpret_cast<const bf16x8*>(&Ast[row][cb]);
  }
}

// ---------------- final node stage fused with pooling ----------------
__global__ __launch_bounds__(512) void node_pool(
    const float* __restrict__ aggH,
    const int* __restrict__ deg,
    const __bf16* __restrict__ w2t,
    const float* __restrict__ b2,
    const int* __restrict__ batch,
    float* __restrict__ sums)          // [NG][128]
{
  __shared__ __bf16 Ast[128][136];
  __shared__ int deg_s[128];
  __shared__ int bs[128];

  const int tid   = threadIdx.x;
  const int lane  = tid & 63;
  const int w     = tid >> 6;
  const int m0    = blockIdx.x * 128;
  const int colq  = lane & 15;
  const int krow  = (lane >> 4) * 8;
  const int rbase = (lane >> 4) * 4;
  const int col   = w * 16 + colq;

  for (int i = tid; i < 128 * 16; i += 512) {
    int row = i >> 4, cb = (i & 15) * 8;
    int g = m0 + row; if (g >= NN) g = NN - 1;
    const float* s = aggH + (size_t)g * H + cb;
    float4 v0 = *reinterpret_cast<const float4*>(s);
    float4 v1 = *reinterpret_cast<const float4*>(s + 4);
    bf16x8 o;
    o[0] = (__bf16)v0.x; o[1] = (__bf16)v0.y; o[2] = (__bf16)v0.z; o[3] = (__bf16)v0.w;
    o[4] = (__bf16)v1.x; o[5] = (__bf16)v1.y; o[6] = (__bf16)v1.z; o[7] = (__bf16)v1.w;
    *reinterpret_cast<bf16x8*>(&Ast[row][cb]) = o;
  }
  if (tid < 128) {
    int g = m0 + tid;
    deg_s[tid] = (g < NN) ? deg[g] : 0;
    bs[tid]    = (g < NN) ? batch[g] : -1;
  }
  __syncthreads();

  bf16x8 w2f[4];
#pragma unroll
  for (int ks = 0; ks < 4; ++ks)
    w2f[ks] = *reinterpret_cast<const bf16x8*>(w2t + (size_t)col * H + ks * 32 + krow);
  const float b2s = b2[col];

  f32x4 acc[8];
#pragma unroll
  for (int mt = 0; mt < 8; ++mt) acc[mt] = (f32x4){0.f, 0.f, 0.f, 0.f};
#pragma unroll
  for (int ks = 0; ks < 4; ++ks)
#pragma unroll
    for (int mt = 0; mt < 8; ++mt) {
      bf16x8 a = *reinterpret_cast<const bf16x8*>(&Ast[mt * 16 + colq][ks * 32 + krow]);
      acc[mt] = __builtin_amdgcn_mfma_f32_16x16x32_bf16(a, w2f[ks], acc[mt], 0, 0, 0);
    }

  // run-accumulate relu(v) by graph id over this thread's 32 ascending rows
  float run = 0.f;
  int cur = -2;
#pragma unroll
  for (int mt = 0; mt < 8; ++mt)
#pragma unroll
    for (int r = 0; r < 4; ++r) {
      int row = mt * 16 + rbase + r;
      int b = bs[row];
      float v = fmaxf(acc[mt][r] + (float)deg_s[row] * b2s, 0.f);
      if (b != cur) {
        if (cur >= 0) atomicAdd(&sums[cur * H + col], run);
        run = 0.f;
        cur = b;
      }
      if (b >= 0) run += v;
    }
  if (cur >= 0) atomicAdd(&sums[cur * H + col], run);
}

// ---------------- edge kernel (edge_mlp4, TPB=4: best measured config) ----------------
template<int DIN>
__global__ __launch_bounds__(512) void edge_mlp4(
    const __bf16* __restrict__ Yb,    // [NN][128]
    const __bf16* __restrict__ eabs,  // [NE][32] sorted
    const int* __restrict__ srcp, const int* __restrict__ dstp,
    const __bf16* __restrict__ w1t,   // [128][DIN]; e-part at col offset F
    const float* __restrict__ b1,
    float* __restrict__ aggH,         // [NN][128] f32
    int ntiles)
{
  constexpr int F = DIN - 32;
  constexpr int TPB = 4;
  __shared__ __bf16 Ylds[128][128];
  __shared__ int dst_s[128];

  const int tid   = threadIdx.x;
  const int lane  = tid & 63;
  const int w     = tid >> 6;
  const int colq  = lane & 15;
  const int krow  = (lane >> 4) * 8;
  const int rbase = (lane >> 4) * 4;
  const int col   = w * 16 + colq;

  const bf16x8 b1f = *reinterpret_cast<const bf16x8*>(w1t + (size_t)col * DIN + F + krow);
  const float  b1s = b1[col];

  const int yrow = tid >> 4;    // 0..31
  const int yc   = tid & 15;
  const int drow = tid & 127;

  int t0 = blockIdx.x * TPB;
  int t1 = t0 + TPB; if (t1 > ntiles) t1 = ntiles;
  if (t0 >= ntiles) return;

  // ---- prologue: tile t0 data; t0+1 src indices ----
  int e0 = t0 * 128;
  int sA[4];
#pragma unroll
  for (int k = 0; k < 4; ++k) sA[k] = srcp[e0 + yrow + 32 * k];
  int dreg = dstp[e0 + drow];
  bf16x8 yreg[4];
#pragma unroll
  for (int k = 0; k < 4; ++k)
    yreg[k] = *reinterpret_cast<const bf16x8*>(Yb + (size_t)sA[k] * H + yc * 8);
  bf16x8 aef[8];
#pragma unroll
  for (int mt = 0; mt < 8; ++mt)
    aef[mt] = *reinterpret_cast<const bf16x8*>(eabs + (size_t)(e0 + mt * 16 + colq) * FE + krow);
  {
    int e0n = (t0 + 1 < t1) ? (t0 + 1) * 128 : e0;
#pragma unroll
    for (int k = 0; k < 4; ++k) sA[k] = srcp[e0n + yrow + 32 * k];
  }

  for (int t = t0; t < t1; ++t) {
    __syncthreads();                     // Ylds free (prev reduce done)
    // stage Y regs -> LDS (rot-swizzled chunks)
#pragma unroll
    for (int k = 0; k < 4; ++k) {
      int row = yrow + 32 * k;
      int cb = (yc * 8 + ((row >> 2) & 3) * 16) & 127;
      *reinterpret_cast<bf16x8*>(&Ylds[row][cb]) = yreg[k];
    }
    if (tid < 128) dst_s[tid] = dreg;
    __syncthreads();                     // stage visible

    // issue next-tile Y/dst gathers (hide under compute)
    if (t + 1 < t1) {
      int e1 = (t + 1) * 128;
#pragma unroll
      for (int k = 0; k < 4; ++k)
        yreg[k] = *reinterpret_cast<const bf16x8*>(Yb + (size_t)sA[k] * H + yc * 8);
      dreg = dstp[e1 + drow];
      int e2 = (t + 2 < t1) ? (t + 2) * 128 : e1;
#pragma unroll
      for (int k = 0; k < 4; ++k) sA[k] = srcp[e2 + yrow + 32 * k];
    }

    // GEMM1e: ea @ W1e + b1 (K=32, one step)
    f32x4 acc[8];
#pragma unroll
    for (int mt = 0; mt < 8; ++mt) acc[mt] = (f32x4){b1s, b1s, b1s, b1s};
#pragma unroll
    for (int mt = 0; mt < 8; ++mt)
      acc[mt] = __builtin_amdgcn_mfma_f32_16x16x32_bf16(aef[mt], b1f, acc[mt], 0, 0, 0);

    // prefetch next-tile ea fragments (aef now dead)
    if (t + 1 < t1) {
      int e1 = (t + 1) * 128;
#pragma unroll
      for (int mt = 0; mt < 8; ++mt)
        aef[mt] = *reinterpret_cast<const bf16x8*>(eabs + (size_t)(e1 + mt * 16 + colq) * FE + krow);
    }

    // in-place: Ylds = relu(Y + ea@W1e + b1)
#pragma unroll
    for (int mt = 0; mt < 8; ++mt)
#pragma unroll
      for (int r = 0; r < 4; ++r) {
        int row = mt * 16 + rbase + r;
        int cs = (col + ((row >> 2) & 3) * 16) & 127;
        float v = (float)Ylds[row][cs] + acc[mt][r];
        Ylds[row][cs] = (__bf16)fmaxf(v, 0.f);
      }
    __syncthreads();                     // Mid complete

    // segment reduce over sorted dst: 4 threads/col, 32 rows each
    {
      const int rc = tid & 127;
      const int r0 = (tid >> 7) * 32;
      float s = 0.f;
      int d = dst_s[r0];
#pragma unroll 4
      for (int r = r0; r < r0 + 32; ++r) {
        int dn = dst_s[r];
        float v = (float)Ylds[r][(rc + ((r >> 2) & 3) * 16) & 127];
        if (dn != d) { atomicAdd(aggH + (size_t)d * H + rc, s); s = 0.f; d = dn; }
        s += v;
      }
      atomicAdd(aggH + (size_t)d * H + rc, s);
    }
  }
}

// ---------------- head: counts via binary search over sorted batch ----------------
__global__ void final_kernel(const float* __restrict__ sums, const int* __restrict__ batch,
                             const float* __restrict__ lw, const float* __restrict__ lb,
                             float* __restrict__ out) {
  int idx = blockIdx.x * blockDim.x + threadIdx.x;
  if (idx >= NG * OD) return;
  int g = idx / OD, o = idx % OD;
  auto lbs = [&](int key) {
    int lo = 0, hi = NN;
    while (lo < hi) {
      int mid = (lo + hi) >> 1;
      if (batch[mid] < key) lo = mid + 1; else hi = mid;
    }
    return lo;
  };
  int c = lbs(g + 1) - lbs(g);
  float inv = 1.f / fmaxf((float)c, 1.f);
  float s = 0.f;
#pragma unroll 8
  for (int k = 0; k < H; ++k)
    s += sums[g * H + k] * lw[k * OD + o];
  out[idx] = s * inv + lb[o];
}

// ---------------- launcher ----------------
extern "C" void kernel_launch(void* const* d_in, const int* in_sizes, int n_in,
                              void* d_out, int out_size, void* d_ws, size_t ws_size,
                              hipStream_t stream) {
  const float* x   = (const float*)d_in[0];
  const int*   ei  = (const int*)d_in[1];
  const float* ea  = (const float*)d_in[2];
  const int*   bat = (const int*)d_in[3];
  const float* w1[3] = {(const float*)d_in[4], (const float*)d_in[8],  (const float*)d_in[12]};
  const float* b1[3] = {(const float*)d_in[5], (const float*)d_in[9],  (const float*)d_in[13]};
  const float* w2[3] = {(const float*)d_in[6], (const float*)d_in[10], (const float*)d_in[14]};
  const float* b2[3] = {(const float*)d_in[7], (const float*)d_in[11], (const float*)d_in[15]};
  const float* lw  = (const float*)d_in[16];
  const float* lb  = (const float*)d_in[17];
  float* out = (float*)d_out;

  char* ws = (char*)d_ws;
  size_t off = 0;
  auto alloc = [&](size_t bytes) -> void* {
    void* p = ws + off;
    off = (off + bytes + 255) & ~(size_t)255;
    return p;
  };
  __bf16* Yb   = (__bf16*)alloc((size_t)NN * H * 2);
  __bf16* eabs = (__bf16*)alloc((size_t)NE * FE * 2);
  __bf16* w1t[3]; __bf16* w2t[3];
  for (int l = 0; l < 3; ++l) {
    w1t[l] = (__bf16*)alloc(128 * 160 * 2);
    w2t[l] = (__bf16*)alloc(128 * 128 * 2);
  }
  // contiguous zero-init region: agg | sums | hist (single memset covers all)
  size_t zoff0 = off;
  float* agg  = (float*)alloc((size_t)NN * H * 4);
  float* sums = (float*)alloc(NG * H * 4);
  int*   hist = (int*)  alloc((size_t)NN * 4);
  size_t zbytes = off - zoff0;
  int* excl   = (int*)alloc((size_t)NN * 4);
  int* btot   = (int*)alloc(256 * 4);
  int* cursor = (int*)alloc((size_t)NN * 4);
  int* srcp   = (int*)alloc((size_t)NE * 4);
  int* dstp   = (int*)alloc((size_t)NE * 4);

  const int* src = ei;
  const int* dst = ei + NE;
  const int NB_SCAN = (NN + 255) / 256;
  const int NTILES = NE / 128;             // 6250
  const int EGRID  = (NTILES + 3) / 4;     // 1563 (TPB=4, best measured)
  const int NGRID  = (NN + 127) / 128;     // 391

  // one memset zeroes agg + sums + hist
  hipMemsetAsync(agg, 0, zbytes, stream);

  // weight conversions (single dispatch)
  cvt_w_all<<<(102400 + 255) / 256, 256, 0, stream>>>(
      w1[0], w1[1], w1[2], w2[0], w2[1], w2[2],
      w1t[0], w1t[1], w1t[2], w2t[0], w2t[1], w2t[2]);

  // counting sort by dst (hist doubles as deg) + fused ea convert/gather
  hist_build<<<(NE + 255) / 256, 256, 0, stream>>>(dst, hist);
  scan1<<<NB_SCAN, 256, 0, stream>>>(hist, excl, btot);
  scan2<<<1, 256, 0, stream>>>(btot, NB_SCAN);
  scan3<<<NB_SCAN, 256, 0, stream>>>(excl, btot, cursor);
  scatter_perm_ea<<<(NE + 255) / 256, 256, 0, stream>>>(src, dst, ea, cursor, srcp, dstp, eabs);

  // ---- layer 0 (f32 x staged+converted in-kernel) ----
  node_gemm2<64, 96, true><<<NGRID, 512, 0, stream>>>(x, w1t[0], Yb);
  edge_mlp4<96><<<EGRID, 512, 0, stream>>>(Yb, eabs, srcp, dstp, w1t[0], b1[0], agg, NTILES);

  // ---- layers 1,2 (node_wy_t zeroes agg for the next accumulate) ----
  for (int l = 1; l < 3; ++l) {
    node_wy_t<<<NGRID, 512, 0, stream>>>(agg, hist, w2t[l - 1], b2[l - 1], w1t[l], Yb);
    edge_mlp4<160><<<EGRID, 512, 0, stream>>>(Yb, eabs, srcp, dstp, w1t[l], b1[l], agg, NTILES);
  }

  // ---- final W2 stage fused with pooling + head ----
  node_pool<<<NGRID, 512, 0, stream>>>(agg, hist, w2t[2], b2[2], bat, sums);
  final_kernel<<<(NG * OD + 255) / 256, 256, 0, stream>>>(sums, bat, lw, lb, out);
}